// Round 1
// baseline (801.378 us; speedup 1.0000x reference)
//
#include <hip/hip_runtime.h>

#define BB   8
#define CIN  64
#define COUT 64
#define HH   128
#define WW   128
#define HWSZ (HH * WW)

// ---------------------------------------------------------------------------
// K1: 3x3 SAME conv x(64ch) -> om(27ch); ch 0..17 = offsets (+bias),
//     ch 18..26 = sigmoid(v + bias) mask. Layout om[b][27][HW].
// ---------------------------------------------------------------------------
__global__ __launch_bounds__(256) void k_offconv(
    const float* __restrict__ x, const float* __restrict__ wof,
    const float* __restrict__ bof, float* __restrict__ om)
{
    const int p = blockIdx.x * 256 + threadIdx.x;   // spatial point
    const int b = blockIdx.y;
    const int h = p >> 7, w = p & 127;

    float acc[27];
#pragma unroll
    for (int o = 0; o < 27; ++o) acc[o] = 0.f;

    const float* xb = x + (size_t)b * CIN * HWSZ;
    for (int c = 0; c < CIN; ++c) {
        const float* xp = xb + c * HWSZ;
        float n[9];
#pragma unroll
        for (int dy = 0; dy < 3; ++dy) {
#pragma unroll
            for (int dx = 0; dx < 3; ++dx) {
                int hh = h + dy - 1, ww = w + dx - 1;
                bool ok = ((unsigned)hh < (unsigned)HH) && ((unsigned)ww < (unsigned)WW);
                n[dy * 3 + dx] = ok ? xp[hh * WW + ww] : 0.f;
            }
        }
#pragma unroll
        for (int o = 0; o < 27; ++o) {
            const float* wp = wof + ((o * CIN) + c) * 9;   // wave-uniform -> s_load
#pragma unroll
            for (int t = 0; t < 9; ++t) acc[o] = fmaf(n[t], wp[t], acc[o]);
        }
    }

    float* omb = om + (size_t)b * 27 * HWSZ + p;
#pragma unroll
    for (int o = 0; o < 18; ++o) omb[o * HWSZ] = acc[o] + bof[o];
#pragma unroll
    for (int o = 18; o < 27; ++o) {
        float v = acc[o] + bof[o];
        omb[o * HWSZ] = 1.f / (1.f + __expf(-v));
    }
}

// ---------------------------------------------------------------------------
// K2: deformable conv. Thread per point, acc over all 64 output channels.
//     Also emits per-block (sum, sumsq) partials per (b,co) for instance norm.
// ---------------------------------------------------------------------------
__global__ __launch_bounds__(256, 2) void k_dcn(
    const float* __restrict__ x, const float* __restrict__ om,
    const float* __restrict__ wd, const float* __restrict__ bd,
    float* __restrict__ out, float2* __restrict__ partial)
{
    const int p = blockIdx.x * 256 + threadIdx.x;
    const int b = blockIdx.y;
    const int h = p >> 7, w = p & 127;

    const float* omp = om + (size_t)b * 27 * HWSZ + p;

    int   adr[9][4];
    float wg[9][4];
#pragma unroll
    for (int k = 0; k < 9; ++k) {
        float offy = omp[(2 * k) * HWSZ];
        float offx = omp[(2 * k + 1) * HWSZ];
        float mk   = omp[(18 + k) * HWSZ];
        float ys = (float)(h + (k / 3) - 1) + offy;
        float xs = (float)(w + (k % 3) - 1) + offx;
        float fy0 = floorf(ys), fx0 = floorf(xs);
        float wy1 = ys - fy0, wx1 = xs - fx0;
        float wy0 = 1.f - wy1, wx0 = 1.f - wx1;
        int y0 = (int)fy0, x0 = (int)fx0;
        int y1 = y0 + 1, x1 = x0 + 1;
        bool vy0 = (y0 >= 0) && (y0 < HH);
        bool vy1 = (y1 >= 0) && (y1 < HH);
        bool vx0 = (x0 >= 0) && (x0 < WW);
        bool vx1 = (x1 >= 0) && (x1 < WW);
        int y0c = min(max(y0, 0), HH - 1), y1c = min(max(y1, 0), HH - 1);
        int x0c = min(max(x0, 0), WW - 1), x1c = min(max(x1, 0), WW - 1);
        adr[k][0] = y0c * WW + x0c;  wg[k][0] = (vy0 && vx0) ? mk * wy0 * wx0 : 0.f;
        adr[k][1] = y0c * WW + x1c;  wg[k][1] = (vy0 && vx1) ? mk * wy0 * wx1 : 0.f;
        adr[k][2] = y1c * WW + x0c;  wg[k][2] = (vy1 && vx0) ? mk * wy1 * wx0 : 0.f;
        adr[k][3] = y1c * WW + x1c;  wg[k][3] = (vy1 && vx1) ? mk * wy1 * wx1 : 0.f;
    }

    float acc[COUT];
#pragma unroll
    for (int co = 0; co < COUT; ++co) acc[co] = 0.f;

    const float* xb = x + (size_t)b * CIN * HWSZ;
    for (int c = 0; c < CIN; ++c) {
        const float* xp = xb + c * HWSZ;
        float col[9];
#pragma unroll
        for (int k = 0; k < 9; ++k) {
            col[k] = wg[k][0] * xp[adr[k][0]] + wg[k][1] * xp[adr[k][1]]
                   + wg[k][2] * xp[adr[k][2]] + wg[k][3] * xp[adr[k][3]];
        }
#pragma unroll
        for (int co = 0; co < COUT; ++co) {
            const float* wp = wd + ((co * CIN) + c) * 9;   // wave-uniform -> s_load
#pragma unroll
            for (int t = 0; t < 9; ++t) acc[co] = fmaf(col[t], wp[t], acc[co]);
        }
    }

    __shared__ float redS[4][COUT];
    __shared__ float redQ[4][COUT];
    const int lane = threadIdx.x & 63;
    const int wid  = threadIdx.x >> 6;

    float* outb = out + ((size_t)b * COUT) * HWSZ + p;
#pragma unroll
    for (int co = 0; co < COUT; ++co) {
        float v = acc[co] + bd[co];
        outb[co * HWSZ] = v;
        float s = v, q = v * v;
#pragma unroll
        for (int m = 1; m < 64; m <<= 1) {
            s += __shfl_xor(s, m);
            q += __shfl_xor(q, m);
        }
        if (lane == 0) { redS[wid][co] = s; redQ[wid][co] = q; }
    }
    __syncthreads();
    if (threadIdx.x < COUT) {
        int co = threadIdx.x;
        float s = redS[0][co] + redS[1][co] + redS[2][co] + redS[3][co];
        float q = redQ[0][co] + redQ[1][co] + redQ[2][co] + redQ[3][co];
        partial[((b * COUT + co) << 6) + blockIdx.x] = make_float2(s, q);
    }
}

// ---------------------------------------------------------------------------
// K3: reduce 64 block-partials per (b,co) -> (mu, rstd)
// ---------------------------------------------------------------------------
__global__ void k_stats(const float2* __restrict__ partial, float2* __restrict__ stats)
{
    const int idx = threadIdx.x;   // 512 threads = b*64 + co
    float s = 0.f, q = 0.f;
    for (int j = 0; j < 64; ++j) {
        float2 v = partial[(idx << 6) + j];
        s += v.x; q += v.y;
    }
    const float inv = 1.f / (float)HWSZ;
    float mu  = s * inv;
    float var = q * inv - mu * mu;
    stats[idx] = make_float2(mu, rsqrtf(var + 1e-5f));
}

// ---------------------------------------------------------------------------
// K4: in-place normalize + ReLU on d_out, float4-vectorized
// ---------------------------------------------------------------------------
__global__ __launch_bounds__(256) void k_norm(float* __restrict__ out,
                                              const float2* __restrict__ stats)
{
    const int i = blockIdx.x * 256 + threadIdx.x;  // float4 index
    float4* o4 = (float4*)out;
    const int bco = i >> 12;                       // (i*4) / 16384
    float2 st = stats[bco];
    float4 v = o4[i];
    v.x = fmaxf((v.x - st.x) * st.y, 0.f);
    v.y = fmaxf((v.y - st.x) * st.y, 0.f);
    v.z = fmaxf((v.z - st.x) * st.y, 0.f);
    v.w = fmaxf((v.w - st.x) * st.y, 0.f);
    o4[i] = v;
}

extern "C" void kernel_launch(void* const* d_in, const int* in_sizes, int n_in,
                              void* d_out, int out_size, void* d_ws, size_t ws_size,
                              hipStream_t stream) {
    const float* x   = (const float*)d_in[0];
    const float* wof = (const float*)d_in[1];
    const float* bof = (const float*)d_in[2];
    const float* wd  = (const float*)d_in[3];
    const float* bd  = (const float*)d_in[4];
    float* out = (float*)d_out;

    char* ws = (char*)d_ws;
    float*  om      = (float*)ws;                    // 8*27*16384*4 = 14,155,776 B
    float2* partial = (float2*)(ws + 14155776);      // 8*64*64*8    =    262,144 B
    float2* stats   = (float2*)(ws + 14417920);      // 512*8        =      4,096 B

    k_offconv<<<dim3(64, 8), 256, 0, stream>>>(x, wof, bof, om);
    k_dcn    <<<dim3(64, 8), 256, 0, stream>>>(x, om, wd, bd, out, partial);
    k_stats  <<<1, 512, 0, stream>>>(partial, stats);
    k_norm   <<<8192, 256, 0, stream>>>(out, stats);
}

// Round 2
// 770.920 us; speedup vs baseline: 1.0395x; 1.0395x over previous
//
#include <hip/hip_runtime.h>

#define BB   8
#define CIN  64
#define COUT 64
#define HH   128
#define WW   128
#define HWSZ (HH * WW)

// ---------------------------------------------------------------------------
// K1: 3x3 SAME conv x(64ch) -> om(27ch); ch 0..17 = offsets (+bias),
//     ch 18..26 = sigmoid(v + bias) mask. Layout om[b][27][HW].
//     Double-buffered c-prefetch: loads for c+1 issued before FMA block of c.
// ---------------------------------------------------------------------------
__global__ __launch_bounds__(256, 4) void k_offconv(
    const float* __restrict__ x, const float* __restrict__ wof,
    const float* __restrict__ bof, float* __restrict__ om)
{
    const int p = blockIdx.x * 256 + threadIdx.x;   // spatial point
    const int b = blockIdx.y;
    const int h = p >> 7, w = p & 127;

    float acc[27];
#pragma unroll
    for (int o = 0; o < 27; ++o) acc[o] = 0.f;

    const float* xb = x + (size_t)b * CIN * HWSZ;

    // neighborhood validity + offsets (c-independent)
    int   noff[9];
    bool  nok[9];
#pragma unroll
    for (int dy = 0; dy < 3; ++dy) {
#pragma unroll
        for (int dx = 0; dx < 3; ++dx) {
            int hh = h + dy - 1, ww = w + dx - 1;
            nok[dy * 3 + dx]  = ((unsigned)hh < (unsigned)HH) && ((unsigned)ww < (unsigned)WW);
            noff[dy * 3 + dx] = min(max(hh, 0), HH - 1) * WW + min(max(ww, 0), WW - 1);
        }
    }

    float nA[9], nB[9];
#pragma unroll
    for (int t = 0; t < 9; ++t) nA[t] = nok[t] ? xb[noff[t]] : 0.f;

    for (int c = 0; c < CIN; c += 2) {
        const float* xp1 = xb + (c + 1) * HWSZ;
#pragma unroll
        for (int t = 0; t < 9; ++t) nB[t] = nok[t] ? xp1[noff[t]] : 0.f;
#pragma unroll
        for (int o = 0; o < 27; ++o) {
            const float* wp = wof + ((o * CIN) + c) * 9;   // wave-uniform -> s_load
#pragma unroll
            for (int t = 0; t < 9; ++t) acc[o] = fmaf(nA[t], wp[t], acc[o]);
        }
        const float* xp2 = xb + min(c + 2, CIN - 1) * HWSZ;
#pragma unroll
        for (int t = 0; t < 9; ++t) nA[t] = nok[t] ? xp2[noff[t]] : 0.f;
#pragma unroll
        for (int o = 0; o < 27; ++o) {
            const float* wp = wof + ((o * CIN) + (c + 1)) * 9;
#pragma unroll
            for (int t = 0; t < 9; ++t) acc[o] = fmaf(nB[t], wp[t], acc[o]);
        }
    }

    float* omb = om + (size_t)b * 27 * HWSZ + p;
#pragma unroll
    for (int o = 0; o < 18; ++o) omb[o * HWSZ] = acc[o] + bof[o];
#pragma unroll
    for (int o = 18; o < 27; ++o) {
        float v = acc[o] + bof[o];
        omb[o * HWSZ] = 1.f / (1.f + __expf(-v));
    }
}

// ---------------------------------------------------------------------------
// K2: deformable conv. Thread per point, acc over all 64 output channels.
//     Single raw prefetch buffer: gathers for channel c+1 are issued before
//     the 576-FMA block of channel c (FMA block = latency cover).
//     Also emits per-block (sum, sumsq) partials per (b,co) for instance norm.
// ---------------------------------------------------------------------------
__global__ __launch_bounds__(256, 2) void k_dcn(
    const float* __restrict__ x, const float* __restrict__ om,
    const float* __restrict__ wd, const float* __restrict__ bd,
    float* __restrict__ out, float2* __restrict__ partial)
{
    const int p = blockIdx.x * 256 + threadIdx.x;
    const int b = blockIdx.y;
    const int h = p >> 7, w = p & 127;

    const float* omp = om + (size_t)b * 27 * HWSZ + p;

    int   adr[9][4];
    float wg[9][4];
#pragma unroll
    for (int k = 0; k < 9; ++k) {
        float offy = omp[(2 * k) * HWSZ];
        float offx = omp[(2 * k + 1) * HWSZ];
        float mk   = omp[(18 + k) * HWSZ];
        float ys = (float)(h + (k / 3) - 1) + offy;
        float xs = (float)(w + (k % 3) - 1) + offx;
        float fy0 = floorf(ys), fx0 = floorf(xs);
        float wy1 = ys - fy0, wx1 = xs - fx0;
        float wy0 = 1.f - wy1, wx0 = 1.f - wx1;
        int y0 = (int)fy0, x0 = (int)fx0;
        int y1 = y0 + 1, x1 = x0 + 1;
        bool vy0 = (y0 >= 0) && (y0 < HH);
        bool vy1 = (y1 >= 0) && (y1 < HH);
        bool vx0 = (x0 >= 0) && (x0 < WW);
        bool vx1 = (x1 >= 0) && (x1 < WW);
        int y0c = min(max(y0, 0), HH - 1), y1c = min(max(y1, 0), HH - 1);
        int x0c = min(max(x0, 0), WW - 1), x1c = min(max(x1, 0), WW - 1);
        adr[k][0] = y0c * WW + x0c;  wg[k][0] = (vy0 && vx0) ? mk * wy0 * wx0 : 0.f;
        adr[k][1] = y0c * WW + x1c;  wg[k][1] = (vy0 && vx1) ? mk * wy0 * wx1 : 0.f;
        adr[k][2] = y1c * WW + x0c;  wg[k][2] = (vy1 && vx0) ? mk * wy1 * wx0 : 0.f;
        adr[k][3] = y1c * WW + x1c;  wg[k][3] = (vy1 && vx1) ? mk * wy1 * wx1 : 0.f;
    }

    float acc[COUT];
#pragma unroll
    for (int co = 0; co < COUT; ++co) acc[co] = 0.f;

    const float* xb = x + (size_t)b * CIN * HWSZ;

    float buf[36];
#pragma unroll
    for (int t = 0; t < 36; ++t) buf[t] = xb[adr[t >> 2][t & 3]];

    for (int c = 0; c < CIN; ++c) {
        // combine current channel's gathered corners (waits on buf loads)
        float col[9];
#pragma unroll
        for (int k = 0; k < 9; ++k) {
            col[k] = wg[k][0] * buf[4 * k] + wg[k][1] * buf[4 * k + 1]
                   + wg[k][2] * buf[4 * k + 2] + wg[k][3] * buf[4 * k + 3];
        }
        // issue next channel's 36 gathers NOW; the FMA block below hides them
        const float* xn = xb + min(c + 1, CIN - 1) * HWSZ;
#pragma unroll
        for (int t = 0; t < 36; ++t) buf[t] = xn[adr[t >> 2][t & 3]];
        // 576 FMAs, co-outer / t-inner keeps s_load_dwordx8 weight batching
#pragma unroll
        for (int co = 0; co < COUT; ++co) {
            const float* wp = wd + ((co * CIN) + c) * 9;
#pragma unroll
            for (int t = 0; t < 9; ++t) acc[co] = fmaf(col[t], wp[t], acc[co]);
        }
    }

    __shared__ float redS[4][COUT];
    __shared__ float redQ[4][COUT];
    const int lane = threadIdx.x & 63;
    const int wid  = threadIdx.x >> 6;

    float* outb = out + ((size_t)b * COUT) * HWSZ + p;
#pragma unroll
    for (int co = 0; co < COUT; ++co) {
        float v = acc[co] + bd[co];
        outb[co * HWSZ] = v;
        float s = v, q = v * v;
#pragma unroll
        for (int m = 1; m < 64; m <<= 1) {
            s += __shfl_xor(s, m);
            q += __shfl_xor(q, m);
        }
        if (lane == 0) { redS[wid][co] = s; redQ[wid][co] = q; }
    }
    __syncthreads();
    if (threadIdx.x < COUT) {
        int co = threadIdx.x;
        float s = redS[0][co] + redS[1][co] + redS[2][co] + redS[3][co];
        float q = redQ[0][co] + redQ[1][co] + redQ[2][co] + redQ[3][co];
        partial[((b * COUT + co) << 6) + blockIdx.x] = make_float2(s, q);
    }
}

// ---------------------------------------------------------------------------
// K3: reduce 64 block-partials per (b,co) -> (mu, rstd)
// ---------------------------------------------------------------------------
__global__ void k_stats(const float2* __restrict__ partial, float2* __restrict__ stats)
{
    const int idx = threadIdx.x;   // 512 threads = b*64 + co
    float s = 0.f, q = 0.f;
    for (int j = 0; j < 64; ++j) {
        float2 v = partial[(idx << 6) + j];
        s += v.x; q += v.y;
    }
    const float inv = 1.f / (float)HWSZ;
    float mu  = s * inv;
    float var = q * inv - mu * mu;
    stats[idx] = make_float2(mu, rsqrtf(var + 1e-5f));
}

// ---------------------------------------------------------------------------
// K4: in-place normalize + ReLU on d_out, float4-vectorized
// ---------------------------------------------------------------------------
__global__ __launch_bounds__(256) void k_norm(float* __restrict__ out,
                                              const float2* __restrict__ stats)
{
    const int i = blockIdx.x * 256 + threadIdx.x;  // float4 index
    float4* o4 = (float4*)out;
    const int bco = i >> 12;                       // (i*4) / 16384
    float2 st = stats[bco];
    float4 v = o4[i];
    v.x = fmaxf((v.x - st.x) * st.y, 0.f);
    v.y = fmaxf((v.y - st.x) * st.y, 0.f);
    v.z = fmaxf((v.z - st.x) * st.y, 0.f);
    v.w = fmaxf((v.w - st.x) * st.y, 0.f);
    o4[i] = v;
}

extern "C" void kernel_launch(void* const* d_in, const int* in_sizes, int n_in,
                              void* d_out, int out_size, void* d_ws, size_t ws_size,
                              hipStream_t stream) {
    const float* x   = (const float*)d_in[0];
    const float* wof = (const float*)d_in[1];
    const float* bof = (const float*)d_in[2];
    const float* wd  = (const float*)d_in[3];
    const float* bd  = (const float*)d_in[4];
    float* out = (float*)d_out;

    char* ws = (char*)d_ws;
    float*  om      = (float*)ws;                    // 8*27*16384*4 = 14,155,776 B
    float2* partial = (float2*)(ws + 14155776);      // 8*64*64*8    =    262,144 B
    float2* stats   = (float2*)(ws + 14417920);      // 512*8        =      4,096 B

    k_offconv<<<dim3(64, 8), 256, 0, stream>>>(x, wof, bof, om);
    k_dcn    <<<dim3(64, 8), 256, 0, stream>>>(x, om, wd, bd, out, partial);
    k_stats  <<<1, 512, 0, stream>>>(partial, stats);
    k_norm   <<<8192, 256, 0, stream>>>(out, stats);
}

// Round 3
// 241.416 us; speedup vs baseline: 3.3195x; 3.1933x over previous
//
#include <hip/hip_runtime.h>

#define BB   8
#define CIN  64
#define COUT 64
#define HH   128
#define WW   128
#define HWSZ (HH * WW)

typedef short bf16x8 __attribute__((ext_vector_type(8)));
typedef float f32x4  __attribute__((ext_vector_type(4)));

__device__ __forceinline__ float blo(unsigned u) { return __uint_as_float(u << 16); }
__device__ __forceinline__ float bhi(unsigned u) { return __uint_as_float(u & 0xffff0000u); }
__device__ __forceinline__ unsigned f2bf_u(float f) {
    unsigned u = __float_as_uint(f);
    return (u + 0x7fffu + ((u >> 16) & 1u)) >> 16;
}
__device__ __forceinline__ unsigned comb1(unsigned a, unsigned b, unsigned c, unsigned d,
                                          float w0, float w1, float w2, float w3) {
    float lo = w0 * blo(a) + w1 * blo(b) + w2 * blo(c) + w3 * blo(d);
    float hi = w0 * bhi(a) + w1 * bhi(b) + w2 * bhi(c) + w3 * bhi(d);
    return (f2bf_u(hi) << 16) | f2bf_u(lo);
}

// ---------------------------------------------------------------------------
// k_tr: x NCHW fp32 -> xT NHWC bf16  (xT[b][p][c], c contiguous)
// ---------------------------------------------------------------------------
__global__ __launch_bounds__(256) void k_tr(const float* __restrict__ x,
                                            unsigned short* __restrict__ xT)
{
    __shared__ unsigned short tile[64][70];
    const int t = threadIdx.x;
    const int b = blockIdx.y;
    const int p0 = blockIdx.x * 64;
#pragma unroll
    for (int i = 0; i < 16; ++i) {
        int c = i * 4 + (t >> 6), pl = t & 63;
        tile[pl][c] = (unsigned short)f2bf_u(x[((size_t)b * 64 + c) * HWSZ + p0 + pl]);
    }
    __syncthreads();
#pragma unroll
    for (int i = 0; i < 16; ++i) {
        int c = t & 63, pl = i * 4 + (t >> 6);
        xT[((size_t)b * HWSZ + p0 + pl) * 64 + c] = tile[pl][c];
    }
}

// ---------------------------------------------------------------------------
// k_wcvt: wd (64co,64c,3,3) -> wdT[k][co][c] bf16 ; wof (27o,64c,3,3) ->
//         wofT[k][32(o,pad0)][c] bf16.  Thread per element, 216*256 = 55296.
// ---------------------------------------------------------------------------
__global__ __launch_bounds__(256) void k_wcvt(const float* __restrict__ wd,
                                              const float* __restrict__ wof,
                                              unsigned short* __restrict__ wdT,
                                              unsigned short* __restrict__ wofT)
{
    int idx = blockIdx.x * 256 + threadIdx.x;
    if (idx < 36864) {
        int k = idx >> 12, rem = idx & 4095, co = rem >> 6, c = rem & 63;
        wdT[idx] = (unsigned short)f2bf_u(wd[(co * 64 + c) * 9 + k]);
    } else {
        int j = idx - 36864;
        int k = j >> 11, rem = j & 2047, o = rem >> 6, c = rem & 63;
        wofT[j] = (o < 27) ? (unsigned short)f2bf_u(wof[(o * 64 + c) * 9 + k]) : 0;
    }
}

// ---------------------------------------------------------------------------
// k_off: offset conv via im2col-in-LDS + MFMA.
//   C[o(32)][p(256)] = sum_k sum_c wofT[k][o][c] * xT[b][p+sh(k)][c]
//   Wave-private 64-point LDS slab -> no barriers.
// ---------------------------------------------------------------------------
__global__ __launch_bounds__(256, 2) void k_off(
    const unsigned short* __restrict__ xT, const unsigned short* __restrict__ wofT,
    const float* __restrict__ bof, float* __restrict__ om)
{
    __shared__ unsigned short col_sh[256 * 72];
    const int t = threadIdx.x;
    const int lane = t & 63, wv = t >> 6;
    const int q = lane >> 4, l15 = lane & 15;
    const int pblk = blockIdx.x * 256;
    const int p = pblk + t;
    const int b = blockIdx.y;
    const int h = p >> 7, w = p & 127;
    const unsigned short* xb = xT + (size_t)b * HWSZ * 64;
    unsigned short* myrow = col_sh + t * 72;

    f32x4 acc[2][4];
#pragma unroll
    for (int mt = 0; mt < 2; ++mt)
#pragma unroll
        for (int nt = 0; nt < 4; ++nt) acc[mt][nt] = (f32x4){0.f, 0.f, 0.f, 0.f};

    for (int k = 0; k < 9; ++k) {
        int hh = h + (k / 3) - 1, ww = w + (k % 3) - 1;
        bool ok = ((unsigned)hh < (unsigned)HH) && ((unsigned)ww < (unsigned)WW);
        int hc = min(max(hh, 0), HH - 1), wc = min(max(ww, 0), WW - 1);
        const uint4* src = (const uint4*)(xb + (size_t)(hc * WW + wc) * 64);
        uint4 z = {0u, 0u, 0u, 0u};
#pragma unroll
        for (int j = 0; j < 8; ++j) {
            uint4 v = src[j];
            ((uint4*)myrow)[j] = ok ? v : z;
        }
        const unsigned short* wk = wofT + k * 2048;
#pragma unroll
        for (int ks = 0; ks < 2; ++ks) {
            bf16x8 af[2], bfr[4];
#pragma unroll
            for (int mt = 0; mt < 2; ++mt)
                af[mt] = *(const bf16x8*)(wk + (mt * 16 + l15) * 64 + ks * 32 + q * 8);
#pragma unroll
            for (int nt = 0; nt < 4; ++nt)
                bfr[nt] = *(const bf16x8*)(col_sh + (wv * 64 + nt * 16 + l15) * 72 + ks * 32 + q * 8);
#pragma unroll
            for (int mt = 0; mt < 2; ++mt)
#pragma unroll
                for (int nt = 0; nt < 4; ++nt)
                    acc[mt][nt] = __builtin_amdgcn_mfma_f32_16x16x32_bf16(
                        af[mt], bfr[nt], acc[mt][nt], 0, 0, 0);
        }
    }

    const int p0 = pblk + wv * 64;
    float* omb = om + (size_t)b * 27 * HWSZ;
#pragma unroll
    for (int mt = 0; mt < 2; ++mt)
#pragma unroll
        for (int r = 0; r < 4; ++r) {
            int o = mt * 16 + q * 4 + r;
            if (o < 27) {
                float bias = bof[o];
#pragma unroll
                for (int nt = 0; nt < 4; ++nt) {
                    int pp = p0 + nt * 16 + l15;
                    float v = acc[mt][nt][r] + bias;
                    if (o >= 18) v = 1.f / (1.f + __expf(-v));
                    omb[(size_t)o * HWSZ + pp] = v;
                }
            }
        }
}

// ---------------------------------------------------------------------------
// k_dcn: per tap k: bilinear-combine 64ch (fp32) -> bf16 LDS row -> MFMA
//   C[co(64)][p(256)] = sum_k sum_c wdT[k][co][c] * col_k[p][c]
//   Wave-private slabs, no barriers.
// ---------------------------------------------------------------------------
__global__ __launch_bounds__(256, 2) void k_dcn(
    const unsigned short* __restrict__ xT, const float* __restrict__ om,
    const unsigned short* __restrict__ wdT, const float* __restrict__ bd,
    float* __restrict__ out)
{
    __shared__ unsigned short col_sh[256 * 72];
    const int t = threadIdx.x;
    const int lane = t & 63, wv = t >> 6;
    const int q = lane >> 4, l15 = lane & 15;
    const int pblk = blockIdx.x * 256;
    const int p = pblk + t;
    const int b = blockIdx.y;
    const int h = p >> 7, w = p & 127;
    const unsigned short* xb = xT + (size_t)b * HWSZ * 64;
    const float* omp = om + (size_t)b * 27 * HWSZ + p;
    unsigned short* myrow = col_sh + t * 72;

    f32x4 acc[4][4];
#pragma unroll
    for (int mt = 0; mt < 4; ++mt)
#pragma unroll
        for (int nt = 0; nt < 4; ++nt) acc[mt][nt] = (f32x4){0.f, 0.f, 0.f, 0.f};

    for (int k = 0; k < 9; ++k) {
        float offy = omp[(2 * k) * HWSZ];
        float offx = omp[(2 * k + 1) * HWSZ];
        float mk   = omp[(18 + k) * HWSZ];
        float ys = (float)(h + (k / 3) - 1) + offy;
        float xs = (float)(w + (k % 3) - 1) + offx;
        float fy0 = floorf(ys), fx0 = floorf(xs);
        float wy1 = ys - fy0, wx1 = xs - fx0;
        float wy0 = 1.f - wy1, wx0 = 1.f - wx1;
        int y0 = (int)fy0, x0 = (int)fx0;
        int y1 = y0 + 1, x1 = x0 + 1;
        bool vy0 = (y0 >= 0) && (y0 < HH), vy1 = (y1 >= 0) && (y1 < HH);
        bool vx0 = (x0 >= 0) && (x0 < WW), vx1 = (x1 >= 0) && (x1 < WW);
        int y0c = min(max(y0, 0), HH - 1), y1c = min(max(y1, 0), HH - 1);
        int x0c = min(max(x0, 0), WW - 1), x1c = min(max(x1, 0), WW - 1);
        float w0 = (vy0 && vx0) ? mk * wy0 * wx0 : 0.f;
        float w1 = (vy0 && vx1) ? mk * wy0 * wx1 : 0.f;
        float w2 = (vy1 && vx0) ? mk * wy1 * wx0 : 0.f;
        float w3 = (vy1 && vx1) ? mk * wy1 * wx1 : 0.f;
        const uint4* ca = (const uint4*)(xb + (size_t)(y0c * WW + x0c) * 64);
        const uint4* cb = (const uint4*)(xb + (size_t)(y0c * WW + x1c) * 64);
        const uint4* cc = (const uint4*)(xb + (size_t)(y1c * WW + x0c) * 64);
        const uint4* cd = (const uint4*)(xb + (size_t)(y1c * WW + x1c) * 64);
#pragma unroll
        for (int j = 0; j < 8; ++j) {
            uint4 A = ca[j], B = cb[j], C = cc[j], D = cd[j];
            uint4 R;
            R.x = comb1(A.x, B.x, C.x, D.x, w0, w1, w2, w3);
            R.y = comb1(A.y, B.y, C.y, D.y, w0, w1, w2, w3);
            R.z = comb1(A.z, B.z, C.z, D.z, w0, w1, w2, w3);
            R.w = comb1(A.w, B.w, C.w, D.w, w0, w1, w2, w3);
            ((uint4*)myrow)[j] = R;
        }
        const unsigned short* wk = wdT + k * 4096;
#pragma unroll
        for (int ks = 0; ks < 2; ++ks) {
            bf16x8 af[4], bfr[4];
#pragma unroll
            for (int mt = 0; mt < 4; ++mt)
                af[mt] = *(const bf16x8*)(wk + (mt * 16 + l15) * 64 + ks * 32 + q * 8);
#pragma unroll
            for (int nt = 0; nt < 4; ++nt)
                bfr[nt] = *(const bf16x8*)(col_sh + (wv * 64 + nt * 16 + l15) * 72 + ks * 32 + q * 8);
#pragma unroll
            for (int mt = 0; mt < 4; ++mt)
#pragma unroll
                for (int nt = 0; nt < 4; ++nt)
                    acc[mt][nt] = __builtin_amdgcn_mfma_f32_16x16x32_bf16(
                        af[mt], bfr[nt], acc[mt][nt], 0, 0, 0);
        }
    }

    const int p0 = pblk + wv * 64;
    float* outb = out + (size_t)b * COUT * HWSZ;
#pragma unroll
    for (int mt = 0; mt < 4; ++mt)
#pragma unroll
        for (int r = 0; r < 4; ++r) {
            int co = mt * 16 + q * 4 + r;
            float bias = bd[co];
#pragma unroll
            for (int nt = 0; nt < 4; ++nt) {
                int pp = p0 + nt * 16 + l15;
                outb[(size_t)co * HWSZ + pp] = acc[mt][nt][r] + bias;
            }
        }
}

// ---------------------------------------------------------------------------
// k_stats: one block per (b,co) plane -> (mu, rstd)
// ---------------------------------------------------------------------------
__global__ __launch_bounds__(256) void k_stats(const float* __restrict__ out,
                                               float2* __restrict__ stats)
{
    const float4* plane = (const float4*)(out + (size_t)blockIdx.x * HWSZ);
    const int t = threadIdx.x;
    const int lane = t & 63, wv = t >> 6;
    float s = 0.f, qq = 0.f;
#pragma unroll
    for (int i = 0; i < 16; ++i) {
        float4 v = plane[i * 256 + t];
        s  += v.x + v.y + v.z + v.w;
        qq += v.x * v.x + v.y * v.y + v.z * v.z + v.w * v.w;
    }
#pragma unroll
    for (int m = 1; m < 64; m <<= 1) {
        s  += __shfl_xor(s, m);
        qq += __shfl_xor(qq, m);
    }
    __shared__ float sS[4], sQ[4];
    if (lane == 0) { sS[wv] = s; sQ[wv] = qq; }
    __syncthreads();
    if (t == 0) {
        s  = sS[0] + sS[1] + sS[2] + sS[3];
        qq = sQ[0] + sQ[1] + sQ[2] + sQ[3];
        float mu  = s / (float)HWSZ;
        float var = qq / (float)HWSZ - mu * mu;
        stats[blockIdx.x] = make_float2(mu, rsqrtf(var + 1e-5f));
    }
}

// ---------------------------------------------------------------------------
// k_norm: in-place normalize + ReLU, float4
// ---------------------------------------------------------------------------
__global__ __launch_bounds__(256) void k_norm(float* __restrict__ out,
                                              const float2* __restrict__ stats)
{
    const int i = blockIdx.x * 256 + threadIdx.x;
    float4* o4 = (float4*)out;
    const int bco = i >> 12;
    float2 st = stats[bco];
    float4 v = o4[i];
    v.x = fmaxf((v.x - st.x) * st.y, 0.f);
    v.y = fmaxf((v.y - st.x) * st.y, 0.f);
    v.z = fmaxf((v.z - st.x) * st.y, 0.f);
    v.w = fmaxf((v.w - st.x) * st.y, 0.f);
    o4[i] = v;
}

extern "C" void kernel_launch(void* const* d_in, const int* in_sizes, int n_in,
                              void* d_out, int out_size, void* d_ws, size_t ws_size,
                              hipStream_t stream) {
    const float* x   = (const float*)d_in[0];
    const float* wof = (const float*)d_in[1];
    const float* bof = (const float*)d_in[2];
    const float* wd  = (const float*)d_in[3];
    const float* bd  = (const float*)d_in[4];
    float* out = (float*)d_out;

    char* ws = (char*)d_ws;
    unsigned short* xT   = (unsigned short*)ws;                  // 16,777,216 B
    float*          om   = (float*)(ws + 16777216);              // 14,155,776 B
    unsigned short* wdT  = (unsigned short*)(ws + 30932992);     //     73,728 B
    unsigned short* wofT = (unsigned short*)(ws + 31006720);     //     36,864 B
    float2*         stats= (float2*)(ws + 31043584);             //      4,096 B

    k_tr   <<<dim3(256, 8), 256, 0, stream>>>(x, xT);
    k_wcvt <<<216, 256, 0, stream>>>(wd, wof, wdT, wofT);
    k_off  <<<dim3(64, 8), 256, 0, stream>>>(xT, wofT, bof, om);
    k_dcn  <<<dim3(64, 8), 256, 0, stream>>>(xT, om, wdT, bd, out);
    k_stats<<<512, 256, 0, stream>>>(out, stats);
    k_norm <<<8192, 256, 0, stream>>>(out, stats);
}

// Round 4
// 182.947 us; speedup vs baseline: 4.3804x; 1.3196x over previous
//
#include <hip/hip_runtime.h>
#include <hip/hip_bf16.h>

#define BB   8
#define CIN  64
#define COUT 64
#define HH   128
#define WW   128
#define HWSZ (HH * WW)

typedef short bf16x8 __attribute__((ext_vector_type(8)));
typedef float f32x4  __attribute__((ext_vector_type(4)));

__device__ __forceinline__ float blo(unsigned u) { return __uint_as_float(u << 16); }
__device__ __forceinline__ float bhi(unsigned u) { return __uint_as_float(u & 0xffff0000u); }
__device__ __forceinline__ unsigned f2bf_u(float f) {
    unsigned u = __float_as_uint(f);
    return (u + 0x7fffu + ((u >> 16) & 1u)) >> 16;
}
__device__ __forceinline__ unsigned comb_pk(unsigned a, unsigned b, unsigned c, unsigned d,
                                            float4 w) {
    float lo = w.x * blo(a) + w.y * blo(b) + w.z * blo(c) + w.w * blo(d);
    float hi = w.x * bhi(a) + w.y * bhi(b) + w.z * bhi(c) + w.w * bhi(d);
    __hip_bfloat162 r = __float22bfloat162_rn(make_float2(lo, hi));  // x->low bits
    return *(unsigned*)&r;
}

// ---------------------------------------------------------------------------
// k_tr: x NCHW fp32 -> xT NHWC bf16. float4 loads, LDS transpose, b128 stores.
// ---------------------------------------------------------------------------
__global__ __launch_bounds__(256) void k_tr(const float* __restrict__ x,
                                            unsigned short* __restrict__ xT)
{
    __shared__ unsigned short tile[256 * 66];   // per-point stride 66 (pad)
    const int t = threadIdx.x;
    const int b = blockIdx.y;
    const int p0 = blockIdx.x * 256;
    // phase1: load float4 (4 consecutive points, one channel), write bf16 to LDS
#pragma unroll
    for (int i = 0; i < 16; ++i) {
        int c = i * 4 + (t >> 6);          // wave-uniform channel
        int pl = (t & 63) * 4;
        float4 v = *(const float4*)(x + (((size_t)b * 64 + c) << 14) + p0 + pl);
        tile[(pl + 0) * 66 + c] = (unsigned short)f2bf_u(v.x);
        tile[(pl + 1) * 66 + c] = (unsigned short)f2bf_u(v.y);
        tile[(pl + 2) * 66 + c] = (unsigned short)f2bf_u(v.z);
        tile[(pl + 3) * 66 + c] = (unsigned short)f2bf_u(v.w);
    }
    __syncthreads();
    // phase2: coalesced b128 stores to xT
#pragma unroll
    for (int i = 0; i < 8; ++i) {
        int id = i * 256 + t;
        int pt = id >> 3, ck = id & 7;
        const unsigned* srcp = (const unsigned*)&tile[pt * 66 + ck * 8];
        uint4 r;
        r.x = srcp[0]; r.y = srcp[1]; r.z = srcp[2]; r.w = srcp[3];
        *(uint4*)(xT + ((size_t)b << 20) + (size_t)(p0 + pt) * 64 + ck * 8) = r;
    }
}

// ---------------------------------------------------------------------------
// k_wcvt: repack weights to bf16 [k][o][c] fragments.
// ---------------------------------------------------------------------------
__global__ __launch_bounds__(256) void k_wcvt(const float* __restrict__ wd,
                                              const float* __restrict__ wof,
                                              unsigned short* __restrict__ wdT,
                                              unsigned short* __restrict__ wofT)
{
    int idx = blockIdx.x * 256 + threadIdx.x;
    if (idx < 36864) {
        int k = idx >> 12, rem = idx & 4095, co = rem >> 6, c = rem & 63;
        wdT[idx] = (unsigned short)f2bf_u(wd[(co * 64 + c) * 9 + k]);
    } else {
        int j = idx - 36864;
        int k = j >> 11, rem = j & 2047, o = rem >> 6, c = rem & 63;
        wofT[j] = (o < 27) ? (unsigned short)f2bf_u(wof[(o * 64 + c) * 9 + k]) : 0;
    }
}

// ---------------------------------------------------------------------------
// k_off: offset conv. Stage 4-row halo tile (chunk-major [m][pt], 64 KB),
//        feed MFMA B-fragments directly from tile; zero-pad via cndmask.
// ---------------------------------------------------------------------------
__global__ __launch_bounds__(256, 2) void k_off(
    const unsigned short* __restrict__ xT, const unsigned short* __restrict__ wofT,
    const float* __restrict__ bof, float* __restrict__ om)
{
    __shared__ unsigned short tile[8 * 4096];   // 65536 B: [m][512 pts][8 ush]
    const int t = threadIdx.x;
    const int lane = t & 63, wv = t >> 6;
    const int q = lane >> 4, l15 = lane & 15;
    const int b = blockIdx.y;
    const int h0 = blockIdx.x * 2;
    const int r0 = h0 - 1;
    const unsigned short* xb = xT + ((size_t)b << 20);

    // stage rows r0..r0+3 (clamped), fully coalesced
#pragma unroll
    for (int i = 0; i < 16; ++i) {
        int id = i * 256 + t;
        int m = id & 7, pt = id >> 3;
        int row = pt >> 7, colp = pt & 127;
        int gy = min(max(r0 + row, 0), HH - 1);
        uint4 v = *(const uint4*)(xb + ((size_t)(gy * WW + colp) << 6) + m * 8);
        *(uint4*)&tile[m * 4096 + pt * 8] = v;
    }
    __syncthreads();

    const int hrow = h0 + (wv >> 1);      // this wave's spatial row
    const int c0 = (wv & 1) * 64;         // this wave's first column

    f32x4 acc[2][4];
#pragma unroll
    for (int mt = 0; mt < 2; ++mt)
#pragma unroll
        for (int nt = 0; nt < 4; ++nt) acc[mt][nt] = (f32x4){0.f, 0.f, 0.f, 0.f};

    const bf16x8 zv = {0, 0, 0, 0, 0, 0, 0, 0};
    for (int k = 0; k < 9; ++k) {
        int ky = k / 3 - 1, kx = k % 3 - 1;
        int gy = hrow + ky;
        bool yok = ((unsigned)gy < (unsigned)HH);
        int trow = gy - r0;               // always in [0,3]
        const unsigned short* wk = wofT + k * 2048;
#pragma unroll
        for (int ks = 0; ks < 2; ++ks) {
            bf16x8 af[2], bfr[4];
#pragma unroll
            for (int mt = 0; mt < 2; ++mt)
                af[mt] = *(const bf16x8*)(wk + (mt * 16 + l15) * 64 + ks * 32 + q * 8);
#pragma unroll
            for (int nt = 0; nt < 4; ++nt) {
                int colp = c0 + nt * 16 + l15;
                int gx = colp + kx;
                bool ok = yok && ((unsigned)gx < (unsigned)WW);
                int gxc = min(max(gx, 0), WW - 1);
                int tpt = trow * 128 + gxc;
                bf16x8 v = *(const bf16x8*)&tile[(ks * 4 + q) * 4096 + tpt * 8];
                bfr[nt] = ok ? v : zv;
            }
#pragma unroll
            for (int mt = 0; mt < 2; ++mt)
#pragma unroll
                for (int nt = 0; nt < 4; ++nt)
                    acc[mt][nt] = __builtin_amdgcn_mfma_f32_16x16x32_bf16(
                        af[mt], bfr[nt], acc[mt][nt], 0, 0, 0);
        }
    }

    const int p0 = blockIdx.x * 256 + wv * 64;
    float* omb = om + (size_t)b * 27 * HWSZ;
#pragma unroll
    for (int mt = 0; mt < 2; ++mt)
#pragma unroll
        for (int r = 0; r < 4; ++r) {
            int o = mt * 16 + q * 4 + r;
            if (o < 27) {
                float bias = bof[o];
#pragma unroll
                for (int nt = 0; nt < 4; ++nt) {
                    int pp = p0 + nt * 16 + l15;
                    float v = acc[mt][nt][r] + bias;
                    if (o >= 18) v = 1.f / (1.f + __expf(-v));
                    omb[(size_t)o * HWSZ + pp] = v;
                }
            }
        }
}

// ---------------------------------------------------------------------------
// k_dcn: cooperative coalesced corner gather + fused bilinear combine -> bf16
//        col in wave-private LDS -> MFMA. Stats partials fused (atomicAdd).
// ---------------------------------------------------------------------------
__global__ __launch_bounds__(256, 2) void k_dcn(
    const unsigned short* __restrict__ xT, const float* __restrict__ om,
    const unsigned short* __restrict__ wdT, const float* __restrict__ bd,
    float* __restrict__ out, float2* __restrict__ sums)
{
    __shared__ unsigned short col_sh[4][64 * 80];   // 40960 B (pt stride 80 ush)
    __shared__ unsigned       adr_sh[4][4][64];     //  4096 B
    __shared__ float4         w_sh[4][64];          //  4096 B
    __shared__ float          redS[4][64];          //  1024 B
    __shared__ float          redQ[4][64];          //  1024 B

    const int t = threadIdx.x;
    const int lane = t & 63, wv = t >> 6;
    const int q = lane >> 4, l15 = lane & 15;
    const int pblk = blockIdx.x * 256;
    const int p = pblk + t;                  // owner point
    const int b = blockIdx.y;
    const int h = p >> 7, w = p & 127;
    const char* xbB = (const char*)(xT + ((size_t)b << 20));
    const float* omp = om + (size_t)b * 27 * HWSZ + p;
    const int gck = lane & 7;

    f32x4 acc[4][4];
#pragma unroll
    for (int mt = 0; mt < 4; ++mt)
#pragma unroll
        for (int nt = 0; nt < 4; ++nt) acc[mt][nt] = (f32x4){0.f, 0.f, 0.f, 0.f};

    for (int k = 0; k < 9; ++k) {
        // --- owner: bilinear corner setup for its point ---
        float offy = omp[(2 * k) * HWSZ];
        float offx = omp[(2 * k + 1) * HWSZ];
        float mk   = omp[(18 + k) * HWSZ];
        float ys = (float)(h + (k / 3) - 1) + offy;
        float xs = (float)(w + (k % 3) - 1) + offx;
        float fy0 = floorf(ys), fx0 = floorf(xs);
        float wy1 = ys - fy0, wx1 = xs - fx0;
        float wy0 = 1.f - wy1, wx0 = 1.f - wx1;
        int y0 = (int)fy0, x0 = (int)fx0;
        int y1 = y0 + 1, x1 = x0 + 1;
        bool vy0 = (y0 >= 0) && (y0 < HH), vy1 = (y1 >= 0) && (y1 < HH);
        bool vx0 = (x0 >= 0) && (x0 < WW), vx1 = (x1 >= 0) && (x1 < WW);
        int y0c = min(max(y0, 0), HH - 1), y1c = min(max(y1, 0), HH - 1);
        int x0c = min(max(x0, 0), WW - 1), x1c = min(max(x1, 0), WW - 1);
        adr_sh[wv][0][lane] = (unsigned)((y0c * WW + x0c) << 7);
        adr_sh[wv][1][lane] = (unsigned)((y0c * WW + x1c) << 7);
        adr_sh[wv][2][lane] = (unsigned)((y1c * WW + x0c) << 7);
        adr_sh[wv][3][lane] = (unsigned)((y1c * WW + x1c) << 7);
        w_sh[wv][lane] = make_float4((vy0 && vx0) ? mk * wy0 * wx0 : 0.f,
                                     (vy0 && vx1) ? mk * wy0 * wx1 : 0.f,
                                     (vy1 && vx0) ? mk * wy1 * wx0 : 0.f,
                                     (vy1 && vx1) ? mk * wy1 * wx1 : 0.f);
        __builtin_amdgcn_wave_barrier();

        // --- cooperative gather+combine: 8-lane groups fetch one point's
        //     corner rows contiguously (coalesced), combine, write col chunk ---
#pragma unroll
        for (int g = 0; g < 8; ++g) {
            int pt = g * 8 + (lane >> 3);
            float4 w4 = w_sh[wv][pt];
            unsigned o0 = adr_sh[wv][0][pt];
            unsigned o1 = adr_sh[wv][1][pt];
            unsigned o2 = adr_sh[wv][2][pt];
            unsigned o3 = adr_sh[wv][3][pt];
            int boff = gck * 16;
            uint4 A = *(const uint4*)(xbB + o0 + boff);
            uint4 Bv = *(const uint4*)(xbB + o1 + boff);
            uint4 C = *(const uint4*)(xbB + o2 + boff);
            uint4 D = *(const uint4*)(xbB + o3 + boff);
            uint4 R;
            R.x = comb_pk(A.x, Bv.x, C.x, D.x, w4);
            R.y = comb_pk(A.y, Bv.y, C.y, D.y, w4);
            R.z = comb_pk(A.z, Bv.z, C.z, D.z, w4);
            R.w = comb_pk(A.w, Bv.w, C.w, D.w, w4);
            *(uint4*)&col_sh[wv][pt * 80 + gck * 8] = R;
        }
        __builtin_amdgcn_wave_barrier();

        // --- MFMA over this tap's K=64 ---
        const unsigned short* wk = wdT + k * 4096;
#pragma unroll
        for (int ks = 0; ks < 2; ++ks) {
            bf16x8 af[4], bfr[4];
#pragma unroll
            for (int mt = 0; mt < 4; ++mt)
                af[mt] = *(const bf16x8*)(wk + (mt * 16 + l15) * 64 + ks * 32 + q * 8);
#pragma unroll
            for (int nt = 0; nt < 4; ++nt)
                bfr[nt] = *(const bf16x8*)&col_sh[wv][(nt * 16 + l15) * 80 + ks * 32 + q * 8];
#pragma unroll
            for (int mt = 0; mt < 4; ++mt)
#pragma unroll
                for (int nt = 0; nt < 4; ++nt)
                    acc[mt][nt] = __builtin_amdgcn_mfma_f32_16x16x32_bf16(
                        af[mt], bfr[nt], acc[mt][nt], 0, 0, 0);
        }
    }

    // --- epilogue: bias add, store, per-(b,co) sum/sumsq partials ---
    const int p0 = pblk + wv * 64;
    float* outb = out + (size_t)b * COUT * HWSZ;
#pragma unroll
    for (int mt = 0; mt < 4; ++mt)
#pragma unroll
        for (int r = 0; r < 4; ++r) {
            int co = mt * 16 + q * 4 + r;
            float bias = bd[co];
            float s = 0.f, qq = 0.f;
#pragma unroll
            for (int nt = 0; nt < 4; ++nt) {
                float v = acc[mt][nt][r] + bias;
                outb[(size_t)co * HWSZ + p0 + nt * 16 + l15] = v;
                s += v; qq += v * v;
            }
#pragma unroll
            for (int m = 1; m < 16; m <<= 1) {
                s += __shfl_xor(s, m);
                qq += __shfl_xor(qq, m);
            }
            if (l15 == 0) { redS[wv][co] = s; redQ[wv][co] = qq; }
        }
    __syncthreads();
    if (t < 64) {
        float S = redS[0][t] + redS[1][t] + redS[2][t] + redS[3][t];
        float Q = redQ[0][t] + redQ[1][t] + redQ[2][t] + redQ[3][t];
        atomicAdd(&sums[b * 64 + t].x, S);
        atomicAdd(&sums[b * 64 + t].y, Q);
    }
}

// ---------------------------------------------------------------------------
// k_stats2: convert (sum,sumsq) -> (mu, rstd) in place. 512 threads total.
// ---------------------------------------------------------------------------
__global__ void k_stats2(float2* __restrict__ sums)
{
    int idx = blockIdx.x * 256 + threadIdx.x;
    float2 sq = sums[idx];
    float mu  = sq.x / (float)HWSZ;
    float var = sq.y / (float)HWSZ - mu * mu;
    sums[idx] = make_float2(mu, rsqrtf(var + 1e-5f));
}

// ---------------------------------------------------------------------------
// k_norm: in-place normalize + ReLU, float4
// ---------------------------------------------------------------------------
__global__ __launch_bounds__(256) void k_norm(float* __restrict__ out,
                                              const float2* __restrict__ stats)
{
    const int i = blockIdx.x * 256 + threadIdx.x;
    float4* o4 = (float4*)out;
    const int bco = i >> 12;
    float2 st = stats[bco];
    float4 v = o4[i];
    v.x = fmaxf((v.x - st.x) * st.y, 0.f);
    v.y = fmaxf((v.y - st.x) * st.y, 0.f);
    v.z = fmaxf((v.z - st.x) * st.y, 0.f);
    v.w = fmaxf((v.w - st.x) * st.y, 0.f);
    o4[i] = v;
}

extern "C" void kernel_launch(void* const* d_in, const int* in_sizes, int n_in,
                              void* d_out, int out_size, void* d_ws, size_t ws_size,
                              hipStream_t stream) {
    const float* x   = (const float*)d_in[0];
    const float* wof = (const float*)d_in[1];
    const float* bof = (const float*)d_in[2];
    const float* wd  = (const float*)d_in[3];
    const float* bd  = (const float*)d_in[4];
    float* out = (float*)d_out;

    char* ws = (char*)d_ws;
    unsigned short* xT   = (unsigned short*)ws;                  // 16,777,216 B
    float*          om   = (float*)(ws + 16777216);              // 14,155,776 B
    unsigned short* wdT  = (unsigned short*)(ws + 30932992);     //     73,728 B
    unsigned short* wofT = (unsigned short*)(ws + 31006720);     //     36,864 B
    float2*         sums = (float2*)(ws + 31043584);             //      4,096 B

    hipMemsetAsync(sums, 0, 4096, stream);
    k_tr    <<<dim3(64, 8), 256, 0, stream>>>(x, xT);
    k_wcvt  <<<216, 256, 0, stream>>>(wd, wof, wdT, wofT);
    k_off   <<<dim3(64, 8), 256, 0, stream>>>(xT, wofT, bof, om);
    k_dcn   <<<dim3(64, 8), 256, 0, stream>>>(xT, om, wdT, bd, out, sums);
    k_stats2<<<2, 256, 0, stream>>>(sums);
    k_norm  <<<8192, 256, 0, stream>>>(out, (const float2*)sums);
}

// Round 6
// 173.059 us; speedup vs baseline: 4.6306x; 1.0571x over previous
//
#include <hip/hip_runtime.h>
#include <hip/hip_bf16.h>

#define BB   8
#define CIN  64
#define COUT 64
#define HH   128
#define WW   128
#define HWSZ (HH * WW)

typedef short bf16x8 __attribute__((ext_vector_type(8)));
typedef float f32x4  __attribute__((ext_vector_type(4)));
typedef float f32x2  __attribute__((ext_vector_type(2)));

__device__ __forceinline__ unsigned f2bf_u(float f) {
    unsigned u = __float_as_uint(f);
    return (u + 0x7fffu + ((u >> 16) & 1u)) >> 16;
}

// packed bilinear combine of one 2-channel pair across 4 corners.
// lo channel = bits[15:0], hi = bits[31:16]; math in fp32 pairs -> v_pk_fma_f32
__device__ __forceinline__ unsigned comb2(unsigned a, unsigned b, unsigned c, unsigned d,
                                          f32x2 W0, f32x2 W1, f32x2 W2, f32x2 W3) {
    f32x2 A = {__uint_as_float(a << 16), __uint_as_float(a & 0xffff0000u)};
    f32x2 B = {__uint_as_float(b << 16), __uint_as_float(b & 0xffff0000u)};
    f32x2 C = {__uint_as_float(c << 16), __uint_as_float(c & 0xffff0000u)};
    f32x2 D = {__uint_as_float(d << 16), __uint_as_float(d & 0xffff0000u)};
    f32x2 r = A * W0;
    r += B * W1;
    r += C * W2;
    r += D * W3;
    __hip_bfloat162 h = __float22bfloat162_rn(make_float2(r.x, r.y));
    return *(const unsigned*)&h;
}

// ---------------------------------------------------------------------------
// k_tr: x NCHW fp32 -> xT NHWC bf16. float4 loads, LDS transpose, b128 stores.
// ---------------------------------------------------------------------------
__global__ __launch_bounds__(256) void k_tr(const float* __restrict__ x,
                                            unsigned short* __restrict__ xT)
{
    __shared__ unsigned short tile[256 * 66];
    const int t = threadIdx.x;
    const int b = blockIdx.y;
    const int p0 = blockIdx.x * 256;
#pragma unroll
    for (int i = 0; i < 16; ++i) {
        int c = i * 4 + (t >> 6);
        int pl = (t & 63) * 4;
        float4 v = *(const float4*)(x + (((size_t)b * 64 + c) << 14) + p0 + pl);
        tile[(pl + 0) * 66 + c] = (unsigned short)f2bf_u(v.x);
        tile[(pl + 1) * 66 + c] = (unsigned short)f2bf_u(v.y);
        tile[(pl + 2) * 66 + c] = (unsigned short)f2bf_u(v.z);
        tile[(pl + 3) * 66 + c] = (unsigned short)f2bf_u(v.w);
    }
    __syncthreads();
#pragma unroll
    for (int i = 0; i < 8; ++i) {
        int id = i * 256 + t;
        int pt = id >> 3, ck = id & 7;
        const unsigned* srcp = (const unsigned*)&tile[pt * 66 + ck * 8];
        uint4 r;
        r.x = srcp[0]; r.y = srcp[1]; r.z = srcp[2]; r.w = srcp[3];
        *(uint4*)(xT + ((size_t)b << 20) + (size_t)(p0 + pt) * 64 + ck * 8) = r;
    }
}

// ---------------------------------------------------------------------------
// k_wcvt: repack weights to bf16 [k][o][c] fragments.
// ---------------------------------------------------------------------------
__global__ __launch_bounds__(256) void k_wcvt(const float* __restrict__ wd,
                                              const float* __restrict__ wof,
                                              unsigned short* __restrict__ wdT,
                                              unsigned short* __restrict__ wofT)
{
    int idx = blockIdx.x * 256 + threadIdx.x;
    if (idx < 36864) {
        int k = idx >> 12, rem = idx & 4095, co = rem >> 6, c = rem & 63;
        wdT[idx] = (unsigned short)f2bf_u(wd[(co * 64 + c) * 9 + k]);
    } else {
        int j = idx - 36864;
        int k = j >> 11, rem = j & 2047, o = rem >> 6, c = rem & 63;
        wofT[j] = (o < 27) ? (unsigned short)f2bf_u(wof[(o * 64 + c) * 9 + k]) : 0;
    }
}

// ---------------------------------------------------------------------------
// k_off: offset conv. 4-row x 130-col ZERO-PADDED halo tile (chunk-major,
//        stride 521 pts to rotate banks). Inner loop = pure ds_read + MFMA,
//        no clamps / cndmask.
// ---------------------------------------------------------------------------
__global__ __launch_bounds__(256, 2) void k_off(
    const unsigned short* __restrict__ xT, const unsigned short* __restrict__ wofT,
    const float* __restrict__ bof, float* __restrict__ om)
{
    __shared__ unsigned short tile[8 * 521 * 8];   // 66,688 B: [m][row*130+col+1][8]
    const int t = threadIdx.x;
    const int lane = t & 63, wv = t >> 6;
    const int q = lane >> 4, l15 = lane & 15;
    const int b = blockIdx.y;
    const int h0 = blockIdx.x * 2;
    const int r0 = h0 - 1;
    const unsigned short* xb = xT + ((size_t)b << 20);

    // stage rows r0..r0+3, cols -1..128, zero-padded OOB. 4160 uint4 total.
#pragma unroll
    for (int i = 0; i < 17; ++i) {
        int id = i * 256 + t;
        if (id < 4160) {
            int m = id & 7, lin = id >> 3;          // lin in [0,520)
            int row = lin / 130, col = lin % 130;
            int gy = r0 + row, gx = col - 1;
            uint4 v = {0u, 0u, 0u, 0u};
            if (((unsigned)gy < (unsigned)HH) && ((unsigned)gx < (unsigned)WW))
                v = *(const uint4*)(xb + ((size_t)(gy * WW + gx) << 6) + m * 8);
            *(uint4*)&tile[(m * 521 + lin) * 8] = v;
        }
    }
    __syncthreads();

    const int hrow = h0 + (wv >> 1);
    const int c0 = (wv & 1) * 64;

    f32x4 acc[2][4];
#pragma unroll
    for (int mt = 0; mt < 2; ++mt)
#pragma unroll
        for (int nt = 0; nt < 4; ++nt) acc[mt][nt] = (f32x4){0.f, 0.f, 0.f, 0.f};

#pragma unroll
    for (int k = 0; k < 9; ++k) {
        const int ky = k / 3 - 1, kx = k % 3 - 1;
        const int trow = (hrow - h0) + ky + 1;     // in [0,3]
        const unsigned short* wk = wofT + k * 2048;
#pragma unroll
        for (int ks = 0; ks < 2; ++ks) {
            bf16x8 af[2], bfr[4];
#pragma unroll
            for (int mt = 0; mt < 2; ++mt)
                af[mt] = *(const bf16x8*)(wk + (mt * 16 + l15) * 64 + ks * 32 + q * 8);
#pragma unroll
            for (int nt = 0; nt < 4; ++nt) {
                int tc = c0 + nt * 16 + l15 + kx + 1;   // in [0,130)
                bfr[nt] = *(const bf16x8*)&tile[((ks * 4 + q) * 521 + trow * 130 + tc) * 8];
            }
#pragma unroll
            for (int mt = 0; mt < 2; ++mt)
#pragma unroll
                for (int nt = 0; nt < 4; ++nt)
                    acc[mt][nt] = __builtin_amdgcn_mfma_f32_16x16x32_bf16(
                        af[mt], bfr[nt], acc[mt][nt], 0, 0, 0);
        }
    }

    const int p0 = blockIdx.x * 256 + wv * 64;
    float* omb = om + (size_t)b * 27 * HWSZ;
#pragma unroll
    for (int mt = 0; mt < 2; ++mt)
#pragma unroll
        for (int r = 0; r < 4; ++r) {
            int o = mt * 16 + q * 4 + r;
            if (o < 27) {
                float bias = bof[o];
#pragma unroll
                for (int nt = 0; nt < 4; ++nt) {
                    int pp = p0 + nt * 16 + l15;
                    float v = acc[mt][nt][r] + bias;
                    if (o >= 18) v = 1.f / (1.f + __expf(-v));
                    omb[(size_t)o * HWSZ + pp] = v;
                }
            }
        }
}

// ---------------------------------------------------------------------------
// k_dcn: coalesced cooperative gather with distance-2 register pipeline,
//        packed-f32x2 bilinear combine, MFMA, fused stats partials.
// ---------------------------------------------------------------------------
__global__ __launch_bounds__(256, 2) void k_dcn(
    const unsigned short* __restrict__ xT, const float* __restrict__ om,
    const unsigned short* __restrict__ wdT, const float* __restrict__ bd,
    float* __restrict__ out, float2* __restrict__ sums)
{
    __shared__ unsigned short col_sh[4][64 * 80];   // 40960 B
    __shared__ unsigned       adr_sh[4][4][64];     //  4096 B
    __shared__ float4         w_sh[4][64];          //  4096 B
    __shared__ float          redS[4][64];          //  1024 B
    __shared__ float          redQ[4][64];          //  1024 B

    const int t = threadIdx.x;
    const int lane = t & 63, wv = t >> 6;
    const int q = lane >> 4, l15 = lane & 15;
    const int pblk = blockIdx.x * 256;
    const int p = pblk + t;
    const int b = blockIdx.y;
    const int h = p >> 7, w = p & 127;
    const char* xbB = (const char*)(xT + ((size_t)b << 20));
    const float* omp = om + (size_t)b * 27 * HWSZ + p;
    const int gck = lane & 7;

    f32x4 acc[4][4];
#pragma unroll
    for (int mt = 0; mt < 4; ++mt)
#pragma unroll
        for (int nt = 0; nt < 4; ++nt) acc[mt][nt] = (f32x4){0.f, 0.f, 0.f, 0.f};

#define LOADG(P, g) { \
    int pt_ = (g) * 8 + (lane >> 3); \
    unsigned o0_ = adr_sh[wv][0][pt_]; \
    unsigned o1_ = adr_sh[wv][1][pt_]; \
    unsigned o2_ = adr_sh[wv][2][pt_]; \
    unsigned o3_ = adr_sh[wv][3][pt_]; \
    int bo_ = gck * 16; \
    P[0] = *(const uint4*)(xbB + o0_ + bo_); \
    P[1] = *(const uint4*)(xbB + o1_ + bo_); \
    P[2] = *(const uint4*)(xbB + o2_ + bo_); \
    P[3] = *(const uint4*)(xbB + o3_ + bo_); }

#define COMBG(P, g) { \
    int pt_ = (g) * 8 + (lane >> 3); \
    float4 w4_ = w_sh[wv][pt_]; \
    f32x2 W0_ = {w4_.x, w4_.x}, W1_ = {w4_.y, w4_.y}; \
    f32x2 W2_ = {w4_.z, w4_.z}, W3_ = {w4_.w, w4_.w}; \
    uint4 R_; \
    R_.x = comb2(P[0].x, P[1].x, P[2].x, P[3].x, W0_, W1_, W2_, W3_); \
    R_.y = comb2(P[0].y, P[1].y, P[2].y, P[3].y, W0_, W1_, W2_, W3_); \
    R_.z = comb2(P[0].z, P[1].z, P[2].z, P[3].z, W0_, W1_, W2_, W3_); \
    R_.w = comb2(P[0].w, P[1].w, P[2].w, P[3].w, W0_, W1_, W2_, W3_); \
    *(uint4*)&col_sh[wv][pt_ * 80 + gck * 8] = R_; }

    // prefetch tap-0 offset/mask
    float offy = omp[0];
    float offx = omp[HWSZ];
    float mk   = omp[18 * HWSZ];

    for (int k = 0; k < 9; ++k) {
        // --- owner: bilinear corner setup for its point (values prefetched) ---
        float ys = (float)(h + (k / 3) - 1) + offy;
        float xs = (float)(w + (k % 3) - 1) + offx;
        float fy0 = floorf(ys), fx0 = floorf(xs);
        float wy1 = ys - fy0, wx1 = xs - fx0;
        float wy0 = 1.f - wy1, wx0 = 1.f - wx1;
        int y0 = (int)fy0, x0 = (int)fx0;
        int y1 = y0 + 1, x1 = x0 + 1;
        bool vy0 = (y0 >= 0) && (y0 < HH), vy1 = (y1 >= 0) && (y1 < HH);
        bool vx0 = (x0 >= 0) && (x0 < WW), vx1 = (x1 >= 0) && (x1 < WW);
        int y0c = min(max(y0, 0), HH - 1), y1c = min(max(y1, 0), HH - 1);
        int x0c = min(max(x0, 0), WW - 1), x1c = min(max(x1, 0), WW - 1);
        adr_sh[wv][0][lane] = (unsigned)((y0c * WW + x0c) << 7);
        adr_sh[wv][1][lane] = (unsigned)((y0c * WW + x1c) << 7);
        adr_sh[wv][2][lane] = (unsigned)((y1c * WW + x0c) << 7);
        adr_sh[wv][3][lane] = (unsigned)((y1c * WW + x1c) << 7);
        w_sh[wv][lane] = make_float4((vy0 && vx0) ? mk * wy0 * wx0 : 0.f,
                                     (vy0 && vx1) ? mk * wy0 * wx1 : 0.f,
                                     (vy1 && vx0) ? mk * wy1 * wx0 : 0.f,
                                     (vy1 && vx1) ? mk * wy1 * wx1 : 0.f);
        // prefetch next tap's offset/mask (k=8 prefetches valid dummies, unused)
        int kn = (k < 8) ? k + 1 : 8;
        offy = omp[(2 * kn) * HWSZ];
        offx = omp[(2 * kn + 1) * HWSZ];
        mk   = omp[(18 + kn) * HWSZ];   // FIX: was (18 + (kn & 7)) — tap 8 read mask[0]
        __builtin_amdgcn_wave_barrier();

        // prefetch this tap's weight fragments early (independent of LDS)
        const unsigned short* wk = wdT + k * 4096;
        bf16x8 af[2][4];
#pragma unroll
        for (int ks = 0; ks < 2; ++ks)
#pragma unroll
            for (int mt = 0; mt < 4; ++mt)
                af[ks][mt] = *(const bf16x8*)(wk + (mt * 16 + l15) * 64 + ks * 32 + q * 8);

        // --- gather + combine, distance-2 software pipeline over 8 groups ---
        uint4 pb[3][4];
        LOADG(pb[0], 0);
        LOADG(pb[1], 1);
#pragma unroll
        for (int g = 0; g < 8; ++g) {
            if (g + 2 < 8) LOADG(pb[(g + 2) % 3], g + 2);
            COMBG(pb[g % 3], g);
        }
        __builtin_amdgcn_wave_barrier();

        // --- MFMA over this tap's K=64 ---
#pragma unroll
        for (int ks = 0; ks < 2; ++ks) {
            bf16x8 bfr[4];
#pragma unroll
            for (int nt = 0; nt < 4; ++nt)
                bfr[nt] = *(const bf16x8*)&col_sh[wv][(nt * 16 + l15) * 80 + ks * 32 + q * 8];
#pragma unroll
            for (int mt = 0; mt < 4; ++mt)
#pragma unroll
                for (int nt = 0; nt < 4; ++nt)
                    acc[mt][nt] = __builtin_amdgcn_mfma_f32_16x16x32_bf16(
                        af[ks][mt], bfr[nt], acc[mt][nt], 0, 0, 0);
        }
    }
#undef LOADG
#undef COMBG

    // --- epilogue: bias add, store, per-(b,co) sum/sumsq partials ---
    const int p0 = pblk + wv * 64;
    float* outb = out + (size_t)b * COUT * HWSZ;
#pragma unroll
    for (int mt = 0; mt < 4; ++mt)
#pragma unroll
        for (int r = 0; r < 4; ++r) {
            int co = mt * 16 + q * 4 + r;
            float bias = bd[co];
            float s = 0.f, qq = 0.f;
#pragma unroll
            for (int nt = 0; nt < 4; ++nt) {
                float v = acc[mt][nt][r] + bias;
                outb[(size_t)co * HWSZ + p0 + nt * 16 + l15] = v;
                s += v; qq += v * v;
            }
#pragma unroll
            for (int m = 1; m < 16; m <<= 1) {
                s += __shfl_xor(s, m);
                qq += __shfl_xor(qq, m);
            }
            if (l15 == 0) { redS[wv][co] = s; redQ[wv][co] = qq; }
        }
    __syncthreads();
    if (t < 64) {
        float S = redS[0][t] + redS[1][t] + redS[2][t] + redS[3][t];
        float Q = redQ[0][t] + redQ[1][t] + redQ[2][t] + redQ[3][t];
        atomicAdd(&sums[b * 64 + t].x, S);
        atomicAdd(&sums[b * 64 + t].y, Q);
    }
}

// ---------------------------------------------------------------------------
// k_norm: in-place normalize + ReLU, float4. Stats computed inline from sums.
// ---------------------------------------------------------------------------
__global__ __launch_bounds__(256) void k_norm(float* __restrict__ out,
                                              const float2* __restrict__ sums)
{
    const int i = blockIdx.x * 256 + threadIdx.x;
    const int bco = i >> 12;                 // uniform per block (256 <= 4096)
    float2 sq = sums[bco];
    float mu  = sq.x * (1.f / (float)HWSZ);
    float var = sq.y * (1.f / (float)HWSZ) - mu * mu;
    float rstd = rsqrtf(var + 1e-5f);
    float4* o4 = (float4*)out;
    float4 v = o4[i];
    v.x = fmaxf((v.x - mu) * rstd, 0.f);
    v.y = fmaxf((v.y - mu) * rstd, 0.f);
    v.z = fmaxf((v.z - mu) * rstd, 0.f);
    v.w = fmaxf((v.w - mu) * rstd, 0.f);
    o4[i] = v;
}

extern "C" void kernel_launch(void* const* d_in, const int* in_sizes, int n_in,
                              void* d_out, int out_size, void* d_ws, size_t ws_size,
                              hipStream_t stream) {
    const float* x   = (const float*)d_in[0];
    const float* wof = (const float*)d_in[1];
    const float* bof = (const float*)d_in[2];
    const float* wd  = (const float*)d_in[3];
    const float* bd  = (const float*)d_in[4];
    float* out = (float*)d_out;

    char* ws = (char*)d_ws;
    unsigned short* xT   = (unsigned short*)ws;                  // 16,777,216 B
    float*          om   = (float*)(ws + 16777216);              // 14,155,776 B
    unsigned short* wdT  = (unsigned short*)(ws + 30932992);     //     73,728 B
    unsigned short* wofT = (unsigned short*)(ws + 31006720);     //     36,864 B
    float2*         sums = (float2*)(ws + 31043584);             //      4,096 B

    hipMemsetAsync(sums, 0, 4096, stream);
    k_tr    <<<dim3(64, 8), 256, 0, stream>>>(x, xT);
    k_wcvt  <<<216, 256, 0, stream>>>(wd, wof, wdT, wofT);
    k_off   <<<dim3(64, 8), 256, 0, stream>>>(xT, wofT, bof, om);
    k_dcn   <<<dim3(64, 8), 256, 0, stream>>>(xT, om, wdT, bd, out, sums);
    k_norm  <<<8192, 256, 0, stream>>>(out, (const float2*)sums);
}